// Round 7
// baseline (205.358 us; speedup 1.0000x reference)
//
#include <hip/hip_runtime.h>
#include <hip/hip_bf16.h>
#include <cstdint>

#define S_LEN 4096
#define D_DIM 512
#define NWIN  511
#define KDIM  8192
#define TROWS 520                 // 8*64+8 x-rows per union A-tile (BM=64)
#define ASLOTS (TROWS * 8)        // 4160 16-byte logical chunks

typedef __attribute__((ext_vector_type(8))) short short8;
typedef __attribute__((ext_vector_type(4))) short short4v;
typedef __attribute__((ext_vector_type(4))) float f32x4;

__device__ __forceinline__ unsigned short f2b(float f) {
    union { float f; unsigned int u; } v; v.f = f;
    unsigned int r = v.u + 0x7FFFu + ((v.u >> 16) & 1u);
    return (unsigned short)(r >> 16);
}

// ---------------------------------------------------------------------------
// Pre-pass: pack W [8192][512] fp32 -> bf16 MFMA-fragment order, c0-major:
// K-step s (t=s>>3, c0=s&7) stored at q=(s&7)*16+(s>>3) so each c0's 16
// t-slices are one contiguous 1 MB stream (per-XCD L2 residency).
// Fragment mapping verified R1-R6:
//   value = W[t*512 + (s&7)*64 + k32*32 + (l>>4)*8 + e][64w + 16n + (l&15)]
//   at short8 slot ((q*8+w)*8 + (n*2+k32))*64 + l.
// ---------------------------------------------------------------------------
__global__ void wpack_kernel(const float* __restrict__ W, short8* __restrict__ pk) {
    __shared__ float tile[64][68];
    const int b2 = blockIdx.x;           // s*8 + w
    const int s = b2 >> 3, w = b2 & 7;
    const int t = s >> 3, c0 = s & 7;
    const int q = c0 * 16 + t;           // c0-major slot
    const int tid = threadIdx.x;
    {
        int r = tid >> 2, c4 = (tid & 3) << 4;
        const float* src = W + (size_t)(t * 512 + c0 * 64 + r) * D_DIM + (w << 6) + c4;
#pragma unroll
        for (int j = 0; j < 4; ++j) {
            float4 v = *(const float4*)(src + 4 * j);
            tile[r][c4 + 4 * j + 0] = v.x;
            tile[r][c4 + 4 * j + 1] = v.y;
            tile[r][c4 + 4 * j + 2] = v.z;
            tile[r][c4 + 4 * j + 3] = v.w;
        }
    }
    __syncthreads();
    const int lane = tid & 63, f2 = tid >> 6;
#pragma unroll
    for (int ff = 0; ff < 2; ++ff) {
        int f = f2 * 2 + ff;
        int n = f >> 1, k32 = f & 1;
        short8 u;
#pragma unroll
        for (int e = 0; e < 8; ++e)
            u[e] = (short)f2b(tile[k32 * 32 + (lane >> 4) * 8 + e][n * 16 + (lane & 15)]);
        pk[((size_t)q * 8 + w) * 8 * 64 + (size_t)f * 64 + lane] = u;
    }
}

__device__ __forceinline__ void load_b(const short8* __restrict__ pk, int q, int wslot,
                                       int lane, short8 (&bf)[4][2]) {
    const short8* base = pk + ((size_t)(q * 8 + wslot) * 8) * 64 + lane;
#pragma unroll
    for (int n = 0; n < 4; ++n)
#pragma unroll
        for (int k32 = 0; k32 < 2; ++k32)
            bf[n][k32] = base[(n * 2 + k32) * 64];
}

// ---------------------------------------------------------------------------
// Fused windows-GEMM + bias + exact GELU + in-block LayerNorm.
// Block: batch b, windows [n0,n0+64). 8 waves; wave w owns cols [64w,64w+64).
// A LDS layout: row = x-row (stride 128 B), 16 slots of 8 B per row,
//   phys_slot = logical_slot ^ sw(row), sw(r) = ((r>>3)&15) ^ (r&1)
//   -> conflict-free ds_read_b64 / ds_write_b64 (16 distinct slots per
//      quarter-wave). Double-buffered (2 x 65 KB), ONE barrier per c0.
// B: fragment-packed pk (c0-major) -> registers, DEPTH-2 prefetch over 4
//   rotating buffers (period 4 | 16 -> identical c0 bodies).
// ---------------------------------------------------------------------------
__global__ __launch_bounds__(512, 1)
void fused_kernel(const float* __restrict__ x,
                  const short8* __restrict__ pk,
                  const float* __restrict__ bias,
                  const float* __restrict__ gamma,
                  const float* __restrict__ beta,
                  float* __restrict__ out)
{
    __shared__ __align__(16) unsigned short lsA[2][TROWS * 64];   // 2 x 65 KB
    __shared__ float redS[8][64];
    __shared__ float redQ[8][64];

    const int blk = blockIdx.x;
    const int b  = blk >> 3;
    const int n0 = (blk & 7) << 6;
    const int tid = threadIdx.x;
    const int lane = tid & 63;
    const int wid  = tid >> 6;
    const int r15 = lane & 15, hi = lane >> 4;
    const float* xb = x + (size_t)b * S_LEN * D_DIM;

    f32x4 acc[4][4] = {};
    short8 b0[4][2], b1[4][2], b2[4][2], b3[4][2];
    float4 ta[2][2];   // staging temps (2 chunks in flight), literal-indexed

#define CISSUE(J, C0N)                                                         \
    {                                                                          \
        if ((J) < 8 || tid < 64) {                                             \
            const int slot = tid + ((J) << 9);                                 \
            const int r = slot >> 3, k8 = slot & 7;                            \
            int grow = 8 * n0 + r;                                             \
            if (grow > S_LEN - 1) grow = S_LEN - 1;                            \
            const float* src = xb + (size_t)grow * D_DIM + ((C0N) << 6) + (k8 << 3); \
            ta[(J) & 1][0] = *(const float4*)src;                              \
            ta[(J) & 1][1] = *(const float4*)(src + 4);                        \
        }                                                                      \
    }

#define CWRITE(J, DST)                                                         \
    {                                                                          \
        if ((J) < 8 || tid < 64) {                                             \
            const int slot = tid + ((J) << 9);                                 \
            const int r = slot >> 3, k8 = slot & 7;                            \
            const int sw = ((r >> 3) & 15) ^ (r & 1);                          \
            short4v lo, hi4;                                                   \
            lo[0] = (short)f2b(ta[(J) & 1][0].x);                              \
            lo[1] = (short)f2b(ta[(J) & 1][0].y);                              \
            lo[2] = (short)f2b(ta[(J) & 1][0].z);                              \
            lo[3] = (short)f2b(ta[(J) & 1][0].w);                              \
            hi4[0] = (short)f2b(ta[(J) & 1][1].x);                             \
            hi4[1] = (short)f2b(ta[(J) & 1][1].y);                             \
            hi4[2] = (short)f2b(ta[(J) & 1][1].z);                             \
            hi4[3] = (short)f2b(ta[(J) & 1][1].w);                             \
            *(short4v*)&(DST)[(r << 6) + ((((k8 << 1)) ^ sw) << 2)]     = lo;  \
            *(short4v*)&(DST)[(r << 6) + ((((k8 << 1) | 1) ^ sw) << 2)] = hi4; \
        }                                                                      \
    }

#define TSTEP(T, LA, BU, BL)                                                   \
    {                                                                          \
        const int qn = (c0 * 16 + (T) + 2) & 127;                              \
        load_b(pk, qn, wid, lane, BL);                                         \
        const int swr = ((r15 + ((T) >> 3)) & 15) ^ ((T) & 1);                 \
        short8 afr[4][2];                                                      \
        _Pragma("unroll")                                                      \
        for (int m = 0; m < 4; ++m) {                                          \
            const int row = (((m << 4) + r15) << 3) + (T);                     \
            _Pragma("unroll")                                                  \
            for (int k32 = 0; k32 < 2; ++k32) {                                \
                const int sl = (k32 << 3) + (hi << 1);                         \
                short4v alo = *(const short4v*)&(LA)[(row << 6) + ((sl ^ swr) << 2)];        \
                short4v ahi = *(const short4v*)&(LA)[(row << 6) + (((sl | 1) ^ swr) << 2)];  \
                afr[m][k32] = __builtin_shufflevector(alo, ahi, 0, 1, 2, 3, 4, 5, 6, 7);     \
            }                                                                  \
        }                                                                      \
        _Pragma("unroll")                                                      \
        for (int k32 = 0; k32 < 2; ++k32)                                      \
            _Pragma("unroll")                                                  \
            for (int m = 0; m < 4; ++m)                                        \
                _Pragma("unroll")                                              \
                for (int n = 0; n < 4; ++n)                                    \
                    acc[m][n] = __builtin_amdgcn_mfma_f32_16x16x32_bf16(       \
                        afr[m][k32], BU[n][k32], acc[m][n], 0, 0, 0);          \
    }

    // ---- prologue: B(q0)->b0, B(q1)->b1, stage A(c0=0) into buf 0 ----
    load_b(pk, 0, wid, lane, b0);
    load_b(pk, 1, wid, lane, b1);
    CISSUE(0, 0) CWRITE(0, lsA[0]) CISSUE(1, 0) CWRITE(1, lsA[0])
    CISSUE(2, 0) CWRITE(2, lsA[0]) CISSUE(3, 0) CWRITE(3, lsA[0])
    CISSUE(4, 0) CWRITE(4, lsA[0]) CISSUE(5, 0) CWRITE(5, lsA[0])
    CISSUE(6, 0) CWRITE(6, lsA[0]) CISSUE(7, 0) CWRITE(7, lsA[0])
    CISSUE(8, 0) CWRITE(8, lsA[0])
    asm volatile("s_waitcnt lgkmcnt(0)" ::: "memory");
    __builtin_amdgcn_s_barrier();
    __builtin_amdgcn_sched_barrier(0);

    // ---- main loop: 8 c0-slices, 16 barrier-free t-steps each ----
    for (int c0 = 0; c0 < 8; ++c0) {
        const unsigned short* La = lsA[c0 & 1];
        unsigned short* Ln = lsA[(c0 + 1) & 1];
        const int c0n = c0 + 1;
        const int pf = (c0 < 7);

        TSTEP(0, La, b0, b2)
        if (pf) { CISSUE(0, c0n) CISSUE(1, c0n) }
        TSTEP(1, La, b1, b3)
        if (pf) { CWRITE(0, Ln) CISSUE(2, c0n) }
        TSTEP(2, La, b2, b0)
        if (pf) { CWRITE(1, Ln) CISSUE(3, c0n) }
        TSTEP(3, La, b3, b1)
        if (pf) { CWRITE(2, Ln) CISSUE(4, c0n) }
        TSTEP(4, La, b0, b2)
        if (pf) { CWRITE(3, Ln) CISSUE(5, c0n) }
        TSTEP(5, La, b1, b3)
        if (pf) { CWRITE(4, Ln) CISSUE(6, c0n) }
        TSTEP(6, La, b2, b0)
        if (pf) { CWRITE(5, Ln) CISSUE(7, c0n) }
        TSTEP(7, La, b3, b1)
        if (pf) { CWRITE(6, Ln) CISSUE(8, c0n) }
        TSTEP(8, La, b0, b2)
        if (pf) { CWRITE(7, Ln) }
        TSTEP(9, La, b1, b3)
        if (pf) { CWRITE(8, Ln) }
        TSTEP(10, La, b2, b0)
        TSTEP(11, La, b3, b1)
        TSTEP(12, La, b0, b2)
        TSTEP(13, La, b1, b3)
        TSTEP(14, La, b2, b0)
        TSTEP(15, La, b3, b1)

        asm volatile("s_waitcnt lgkmcnt(0)" ::: "memory");
        __builtin_amdgcn_s_barrier();
        __builtin_amdgcn_sched_barrier(0);
    }
#undef TSTEP
#undef CISSUE
#undef CWRITE

    // ---- epilogue: bias + exact GELU + LayerNorm (verified R3/R6) ----
    float bias4[4], gam4[4], bet4[4];
#pragma unroll
    for (int n = 0; n < 4; ++n) {
        int d = (wid << 6) + 16 * n + r15;
        bias4[n] = bias[d]; gam4[n] = gamma[d]; bet4[n] = beta[d];
    }
    float sum_[4][4], sq_[4][4];
#pragma unroll
    for (int m = 0; m < 4; ++m)
#pragma unroll
        for (int r = 0; r < 4; ++r) { sum_[m][r] = 0.f; sq_[m][r] = 0.f; }
#pragma unroll
    for (int m = 0; m < 4; ++m)
#pragma unroll
        for (int n = 0; n < 4; ++n)
#pragma unroll
            for (int r = 0; r < 4; ++r) {
                float h = acc[m][n][r] + bias4[n];
                float g = 0.5f * h * (1.0f + erff(h * 0.70710678118654752f));
                acc[m][n][r] = g;
                sum_[m][r] += g;
                sq_[m][r]  += g * g;
            }
#pragma unroll
    for (int m = 0; m < 4; ++m)
#pragma unroll
        for (int r = 0; r < 4; ++r) {
            float sv = sum_[m][r], qv = sq_[m][r];
#pragma unroll
            for (int msk = 1; msk < 16; msk <<= 1) {
                sv += __shfl_xor(sv, msk, 64);
                qv += __shfl_xor(qv, msk, 64);
            }
            sum_[m][r] = sv; sq_[m][r] = qv;
        }
    if (r15 == 0) {
#pragma unroll
        for (int m = 0; m < 4; ++m)
#pragma unroll
            for (int r = 0; r < 4; ++r) {
                int row16 = 16 * m + hi * 4 + r;
                redS[wid][row16] = sum_[m][r];
                redQ[wid][row16] = sq_[m][r];
            }
    }
    __syncthreads();
#pragma unroll
    for (int m = 0; m < 4; ++m) {
#pragma unroll
        for (int r = 0; r < 4; ++r) {
            int row16 = 16 * m + hi * 4 + r;
            float sv = 0.f, qv = 0.f;
#pragma unroll
            for (int w = 0; w < 8; ++w) { sv += redS[w][row16]; qv += redQ[w][row16]; }
            float mu  = sv * (1.0f / 512.0f);
            float var = qv * (1.0f / 512.0f) - mu * mu;
            float inv = rsqrtf(var + 1e-5f);
            int win = n0 + row16;
            if (win < NWIN) {
                size_t obase = ((size_t)b * NWIN + win) * D_DIM;
#pragma unroll
                for (int n = 0; n < 4; ++n) {
                    int d = (wid << 6) + 16 * n + r15;
                    out[obase + d] = (acc[m][n][r] - mu) * inv * gam4[n] + bet4[n];
                }
            }
        }
    }
}

// Fallback (tiny ws): naive correct kernel.
__global__ void naive_kernel(const float* __restrict__ x, const float* __restrict__ W,
                             const float* __restrict__ bias, const float* __restrict__ gamma,
                             const float* __restrict__ beta, float* __restrict__ out) {
    __shared__ float hrow[D_DIM];
    __shared__ float red[2];
    const int b = blockIdx.x / NWIN, win = blockIdx.x % NWIN;
    const int d = threadIdx.x;
    float a = 0.f;
    for (int t = 0; t < 16; ++t) {
        const float* xr = x + ((size_t)b * S_LEN + 8 * win + t) * D_DIM;
        const float* wr = W + (size_t)t * D_DIM * D_DIM;
        for (int k = 0; k < D_DIM; ++k) a += xr[k] * wr[(size_t)k * D_DIM + d];
    }
    a += bias[d];
    a = 0.5f * a * (1.0f + erff(a * 0.70710678118654752f));
    hrow[d] = a;
    __syncthreads();
    if (d == 0) {
        float s = 0.f, q = 0.f;
        for (int k = 0; k < D_DIM; ++k) { s += hrow[k]; q += hrow[k] * hrow[k]; }
        float mu = s / D_DIM;
        red[0] = mu; red[1] = rsqrtf(q / D_DIM - mu * mu + 1e-5f);
    }
    __syncthreads();
    out[((size_t)b * NWIN + win) * D_DIM + d] = (a - red[0]) * red[1] * gamma[d] + beta[d];
}

extern "C" void kernel_launch(void* const* d_in, const int* in_sizes, int n_in,
                              void* d_out, int out_size, void* d_ws, size_t ws_size,
                              hipStream_t stream) {
    const float* x     = (const float*)d_in[0];
    const float* W     = (const float*)d_in[1];
    const float* bias  = (const float*)d_in[2];
    const float* gamma = (const float*)d_in[3];
    const float* beta  = (const float*)d_in[4];
    float* out = (float*)d_out;

    const size_t pk_bytes = (size_t)KDIM * D_DIM * sizeof(unsigned short);  // 8 MB
    if (ws_size >= pk_bytes) {
        short8* pk = (short8*)d_ws;
        wpack_kernel<<<1024, 256, 0, stream>>>(W, pk);
        fused_kernel<<<256, 512, 0, stream>>>(x, pk, bias, gamma, beta, out);
    } else {
        naive_kernel<<<32 * NWIN, D_DIM, 0, stream>>>(x, W, bias, gamma, beta, out);
    }
}